// Round 4
// baseline (119.078 us; speedup 1.0000x reference)
//
#include <hip/hip_runtime.h>
#include <math.h>

// Constants: MASS=1.0, CHARGE=0.5, ALPHA=0.1, BETA=0.05, ETA=(+1,-1,-1,-1)
// f64 replica of the JAX reference. Key semantic: jnp.linalg.pinv default
// rcond = 10 * max(M,N) * eps(float32) = 4.76837158203125e-6; singular
// values (=|eigenvalues| for symmetric J_uu) <= rcond*sigma_max are ZEROED.

__global__ __launch_bounds__(256) void rel_particle_kernel(
    const float* __restrict__ y, const float* __restrict__ W,
    const float* __restrict__ V, float* __restrict__ out, int B)
{
    __shared__ double sW[16], sV[16];
    if (threadIdx.x < 16)      sW[threadIdx.x]      = (double)W[threadIdx.x];
    else if (threadIdx.x < 32) sV[threadIdx.x - 16] = (double)V[threadIdx.x - 16];
    __syncthreads();

    int i = blockIdx.x * blockDim.x + threadIdx.x;
    if (i >= B) return;

    const float4* y4 = (const float4*)y;
    float4 xv = y4[2 * i];
    float4 uv = y4[2 * i + 1];
    double x[4] = {xv.x, xv.y, xv.z, xv.w};
    double u[4] = {uv.x, uv.y, uv.z, uv.w};
    const double eta[4] = {1.0, -1.0, -1.0, -1.0};
    const double CHG = 0.5, ALPHA = 0.1, BETA = 0.05;

    // A_j = tanh((Wx)_j) + (Vx)_j ; G[j][k] = dA_j/dx_k
    double A[4], G[4][4];
    #pragma unroll
    for (int j = 0; j < 4; ++j) {
        double t = 0.0, s = 0.0;
        #pragma unroll
        for (int k = 0; k < 4; ++k) {
            t += sW[j * 4 + k] * x[k];
            s += sV[j * 4 + k] * x[k];
        }
        double th = tanh(t);
        A[j] = th + s;
        double dth = 1.0 - th * th;
        #pragma unroll
        for (int k = 0; k < 4; ++k)
            G[j][k] = dth * sW[j * 4 + k] + sV[j * 4 + k];
    }

    double S = 0.0;
    #pragma unroll
    for (int k = 0; k < 4; ++k) S += u[k] * A[k];

    // P = G^T u, R = G u, Q_j = sum_k G[k][j]*CHG*eta_k*u_k, T = u^T G u
    double P[4], R[4], Q[4];
    #pragma unroll
    for (int j = 0; j < 4; ++j) {
        double p = 0.0, r = 0.0, q = 0.0;
        #pragma unroll
        for (int k = 0; k < 4; ++k) {
            p += G[k][j] * u[k];
            r += G[j][k] * u[k];
            q += G[k][j] * (CHG * eta[k]) * u[k];
        }
        P[j] = p; R[j] = r; Q[j] = q;
    }
    double T = 0.0;
    #pragma unroll
    for (int j = 0; j < 4; ++j) T += u[j] * R[j];

    double f[4];
    #pragma unroll
    for (int j = 0; j < 4; ++j) {
        f[j] = -2.0 * ALPHA * x[j] * u[j] * u[j]
             + Q[j]
             + 2.0 * BETA * S * P[j]
             - (CHG * eta[j] + 2.0 * BETA * S) * R[j]
             - 2.0 * BETA * A[j] * T;
    }

    // J_uu = diag(eta_i + 2*ALPHA*x_i^2) + 2*BETA * A A^T  (symmetric, indefinite)
    double M[4][4], Vm[4][4];
    #pragma unroll
    for (int r = 0; r < 4; ++r) {
        #pragma unroll
        for (int c2 = 0; c2 < 4; ++c2) {
            M[r][c2] = 2.0 * BETA * A[r] * A[c2];
            Vm[r][c2] = (r == c2) ? 1.0 : 0.0;
        }
        M[r][r] += eta[r] + 2.0 * ALPHA * x[r] * x[r];
    }

    // Cyclic Jacobi eigendecomposition (f64), 8 sweeps -> machine precision
    for (int sweep = 0; sweep < 8; ++sweep) {
        #pragma unroll
        for (int p = 0; p < 3; ++p) {
            #pragma unroll
            for (int q2 = p + 1; q2 < 4; ++q2) {
                double apq = M[p][q2];
                if (fabs(apq) < 1e-280) continue;
                double app = M[p][p], aqq = M[q2][q2];
                double tau = (aqq - app) / (2.0 * apq);
                double tt = ((tau >= 0.0) ? 1.0 : -1.0) /
                            (fabs(tau) + sqrt(1.0 + tau * tau));
                double c = 1.0 / sqrt(1.0 + tt * tt);
                double s = tt * c;
                #pragma unroll
                for (int k = 0; k < 4; ++k) {
                    double mkp = M[k][p], mkq = M[k][q2];
                    M[k][p]  = c * mkp - s * mkq;
                    M[k][q2] = s * mkp + c * mkq;
                }
                #pragma unroll
                for (int k = 0; k < 4; ++k) {
                    double mpk = M[p][k], mqk = M[q2][k];
                    M[p][k]  = c * mpk - s * mqk;
                    M[q2][k] = s * mpk + c * mqk;
                }
                #pragma unroll
                for (int k = 0; k < 4; ++k) {
                    double vkp = Vm[k][p], vkq = Vm[k][q2];
                    Vm[k][p]  = c * vkp - s * vkq;
                    Vm[k][q2] = s * vkp + c * vkq;
                }
            }
        }
    }

    // jax pinv semantics: cutoff = 10*max(M,N)*eps_f32 * sigma_max;
    // keep strictly-greater singular values (|lambda|).
    double lam[4];
    double sigmax = 0.0;
    #pragma unroll
    for (int k = 0; k < 4; ++k) {
        lam[k] = M[k][k];
        double a = fabs(lam[k]);
        sigmax = (a > sigmax) ? a : sigmax;
    }
    double cutoff = 4.76837158203125e-6 * sigmax;

    double acc[4] = {0.0, 0.0, 0.0, 0.0};
    #pragma unroll
    for (int e = 0; e < 4; ++e) {
        if (fabs(lam[e]) > cutoff) {
            double coef = 0.0;
            #pragma unroll
            for (int k = 0; k < 4; ++k) coef += Vm[k][e] * f[k];
            coef /= lam[e];
            #pragma unroll
            for (int j = 0; j < 4; ++j) acc[j] += coef * Vm[j][e];
        }
    }

    float4 res;
    res.x = (float)acc[0];
    res.y = (float)acc[1];
    res.z = (float)acc[2];
    res.w = (float)acc[3];
    ((float4*)out)[i] = res;
}

extern "C" void kernel_launch(void* const* d_in, const int* in_sizes, int n_in,
                              void* d_out, int out_size, void* d_ws, size_t ws_size,
                              hipStream_t stream) {
    const float* y = (const float*)d_in[0];
    const float* W = (const float*)d_in[1];
    const float* V = (const float*)d_in[2];
    float* out = (float*)d_out;
    int B = in_sizes[0] / 8;
    int block = 256;
    int grid = (B + block - 1) / block;
    rel_particle_kernel<<<grid, block, 0, stream>>>(y, W, V, out, B);
}

// Round 5
// 98.322 us; speedup vs baseline: 1.2111x; 1.2111x over previous
//
#include <hip/hip_runtime.h>
#include <math.h>

// Constants: MASS=1.0, CHARGE=0.5, ALPHA=0.1, BETA=0.05, ETA=(+1,-1,-1,-1)
// f64 replica of the JAX reference. jnp.linalg.pinv default rcond
//   = 10*max(M,N)*eps_f32 = 4.76837158203125e-6 (verified round 4).
// Fast path: if det/sigma bounds PROVE min|lambda| > 6x cutoff, pinv == inv
// and Sherman-Morrison (exact in f64) replaces the Jacobi eigensolver.
// Slow path (rare): round-4 Jacobi + truncation, unchanged.

__global__ __launch_bounds__(256) void rel_particle_kernel(
    const float* __restrict__ y, const float* __restrict__ W,
    const float* __restrict__ V, float* __restrict__ out, int B)
{
    __shared__ double sW[16], sV[16];
    if (threadIdx.x < 16)      sW[threadIdx.x]      = (double)W[threadIdx.x];
    else if (threadIdx.x < 32) sV[threadIdx.x - 16] = (double)V[threadIdx.x - 16];
    __syncthreads();

    int i = blockIdx.x * blockDim.x + threadIdx.x;
    if (i >= B) return;

    const float4* y4 = (const float4*)y;
    float4 xv = y4[2 * i];
    float4 uv = y4[2 * i + 1];
    double x[4] = {xv.x, xv.y, xv.z, xv.w};
    double u[4] = {uv.x, uv.y, uv.z, uv.w};
    const double eta[4] = {1.0, -1.0, -1.0, -1.0};
    const double CHG = 0.5, ALPHA = 0.1, BETA = 0.05;
    const double C2 = 2.0 * BETA;  // 0.1, coefficient of A A^T in J_uu

    // A_j = tanh((Wx)_j) + (Vx)_j ; G[j][k] = dA_j/dx_k  (f64: A feeds J_uu,
    // near-cutoff eigenvalues need ~1e-8 absolute accuracy in A)
    double A[4], G[4][4];
    #pragma unroll
    for (int j = 0; j < 4; ++j) {
        double t = 0.0, s = 0.0;
        #pragma unroll
        for (int k = 0; k < 4; ++k) {
            t += sW[j * 4 + k] * x[k];
            s += sV[j * 4 + k] * x[k];
        }
        double th = tanh(t);
        A[j] = th + s;
        double dth = 1.0 - th * th;
        #pragma unroll
        for (int k = 0; k < 4; ++k)
            G[j][k] = dth * sW[j * 4 + k] + sV[j * 4 + k];
    }

    double S = 0.0;
    #pragma unroll
    for (int k = 0; k < 4; ++k) S += u[k] * A[k];

    // P = G^T u, R = G u, Q_j = sum_k G[k][j]*CHG*eta_k*u_k, T = u^T G u
    double P[4], R[4], Q[4];
    #pragma unroll
    for (int j = 0; j < 4; ++j) {
        double p = 0.0, r = 0.0, q = 0.0;
        #pragma unroll
        for (int k = 0; k < 4; ++k) {
            p += G[k][j] * u[k];
            r += G[j][k] * u[k];
            q += G[k][j] * (CHG * eta[k]) * u[k];
        }
        P[j] = p; R[j] = r; Q[j] = q;
    }
    double T = 0.0;
    #pragma unroll
    for (int j = 0; j < 4; ++j) T += u[j] * R[j];

    double f[4];
    #pragma unroll
    for (int j = 0; j < 4; ++j) {
        f[j] = -2.0 * ALPHA * x[j] * u[j] * u[j]
             + Q[j]
             + 2.0 * BETA * S * P[j]
             - (CHG * eta[j] + 2.0 * BETA * S) * R[j]
             - 2.0 * BETA * A[j] * T;
    }

    // J_uu = diag(d) + C2 * A A^T,  d_i = eta_i + 2*ALPHA*x_i^2
    double d[4], mind = 1e300;
    #pragma unroll
    for (int j = 0; j < 4; ++j) {
        d[j] = eta[j] + 2.0 * ALPHA * x[j] * x[j];
        double a = fabs(d[j]);
        mind = (a < mind) ? a : mind;
    }

    // det(J) = prod(d) + C2 * sum_i A_i^2 * prod_{j!=i} d_j   (division-free)
    double p01 = d[0] * d[1], p23 = d[2] * d[3];
    double det = p01 * p23;
    {
        double padj0 = d[1] * p23, padj1 = d[0] * p23;
        double padj2 = p01 * d[3], padj3 = p01 * d[2];
        det += C2 * (A[0]*A[0]*padj0 + A[1]*A[1]*padj1 +
                     A[2]*A[2]*padj2 + A[3]*A[3]*padj3);
    }

    // sigma_max upper bound: min(Frobenius, max row sum)
    double sumA2 = 0.0, sumA4 = 0.0, F2 = 0.0;
    #pragma unroll
    for (int j = 0; j < 4; ++j) {
        double Aj2 = A[j] * A[j];
        sumA2 += Aj2; sumA4 += Aj2 * Aj2;
        double Jjj = d[j] + C2 * Aj2;
        F2 += Jjj * Jjj;
    }
    F2 += C2 * C2 * (sumA2 * sumA2 - sumA4);
    double rowmax = 0.0;
    #pragma unroll
    for (int r = 0; r < 4; ++r) {
        double rs = 0.0;
        #pragma unroll
        for (int c = 0; c < 4; ++c) {
            double Jrc = C2 * A[r] * A[c] + ((r == c) ? d[r] : 0.0);
            rs += fabs(Jrc);
        }
        rowmax = (rs > rowmax) ? rs : rowmax;
    }
    double sig_hi2 = rowmax * rowmax;
    sig_hi2 = (F2 < sig_hi2) ? F2 : sig_hi2;   // sigma_max^2 <= sig_hi2
    // safe  <=>  |det| > 6 * rcond * sig_hi^4   =>  min|lambda| > 6*cutoff
    bool safe = (fabs(det) > 2.8610229e-5 * sig_hi2 * sig_hi2) && (mind > 1e-3);

    double acc[4];
    if (safe) {
        // pinv == inverse; Sherman-Morrison in f64 (exact to ~1e-12 here)
        double b[4], fd[4], den = 1.0, w = 0.0;
        #pragma unroll
        for (int j = 0; j < 4; ++j) {
            double inv = 1.0 / d[j];
            b[j]  = A[j] * inv;
            fd[j] = f[j] * inv;
            den  += C2 * A[j] * b[j];
            w    += b[j] * f[j];
        }
        double scale = C2 * w / den;
        #pragma unroll
        for (int j = 0; j < 4; ++j) acc[j] = fd[j] - b[j] * scale;
    } else {
        // Rare path: full Jacobi eigendecomposition + jax-pinv truncation
        double M[4][4], Vm[4][4];
        #pragma unroll
        for (int r = 0; r < 4; ++r) {
            #pragma unroll
            for (int c2i = 0; c2i < 4; ++c2i) {
                M[r][c2i] = C2 * A[r] * A[c2i];
                Vm[r][c2i] = (r == c2i) ? 1.0 : 0.0;
            }
            M[r][r] += d[r];
        }
        for (int sweep = 0; sweep < 8; ++sweep) {
            #pragma unroll
            for (int p = 0; p < 3; ++p) {
                #pragma unroll
                for (int q2 = p + 1; q2 < 4; ++q2) {
                    double apq = M[p][q2];
                    if (fabs(apq) < 1e-280) continue;
                    double app = M[p][p], aqq = M[q2][q2];
                    double tau = (aqq - app) / (2.0 * apq);
                    double tt = ((tau >= 0.0) ? 1.0 : -1.0) /
                                (fabs(tau) + sqrt(1.0 + tau * tau));
                    double c = 1.0 / sqrt(1.0 + tt * tt);
                    double s = tt * c;
                    #pragma unroll
                    for (int k = 0; k < 4; ++k) {
                        double mkp = M[k][p], mkq = M[k][q2];
                        M[k][p]  = c * mkp - s * mkq;
                        M[k][q2] = s * mkp + c * mkq;
                    }
                    #pragma unroll
                    for (int k = 0; k < 4; ++k) {
                        double mpk = M[p][k], mqk = M[q2][k];
                        M[p][k]  = c * mpk - s * mqk;
                        M[q2][k] = s * mpk + c * mqk;
                    }
                    #pragma unroll
                    for (int k = 0; k < 4; ++k) {
                        double vkp = Vm[k][p], vkq = Vm[k][q2];
                        Vm[k][p]  = c * vkp - s * vkq;
                        Vm[k][q2] = s * vkp + c * vkq;
                    }
                }
            }
        }
        double lam[4], sigmax = 0.0;
        #pragma unroll
        for (int k = 0; k < 4; ++k) {
            lam[k] = M[k][k];
            double a = fabs(lam[k]);
            sigmax = (a > sigmax) ? a : sigmax;
        }
        double cutoff = 4.76837158203125e-6 * sigmax;
        #pragma unroll
        for (int j = 0; j < 4; ++j) acc[j] = 0.0;
        #pragma unroll
        for (int e = 0; e < 4; ++e) {
            if (fabs(lam[e]) > cutoff) {
                double coef = 0.0;
                #pragma unroll
                for (int k = 0; k < 4; ++k) coef += Vm[k][e] * f[k];
                coef /= lam[e];
                #pragma unroll
                for (int j = 0; j < 4; ++j) acc[j] += coef * Vm[j][e];
            }
        }
    }

    float4 res;
    res.x = (float)acc[0];
    res.y = (float)acc[1];
    res.z = (float)acc[2];
    res.w = (float)acc[3];
    ((float4*)out)[i] = res;
}

extern "C" void kernel_launch(void* const* d_in, const int* in_sizes, int n_in,
                              void* d_out, int out_size, void* d_ws, size_t ws_size,
                              hipStream_t stream) {
    const float* y = (const float*)d_in[0];
    const float* W = (const float*)d_in[1];
    const float* V = (const float*)d_in[2];
    float* out = (float*)d_out;
    int B = in_sizes[0] / 8;
    int block = 256;
    int grid = (B + block - 1) / block;
    rel_particle_kernel<<<grid, block, 0, stream>>>(y, W, V, out, B);
}

// Round 6
// 88.360 us; speedup vs baseline: 1.3476x; 1.1127x over previous
//
#include <hip/hip_runtime.h>
#include <math.h>

// Constants: MASS=1.0, CHARGE=0.5, ALPHA=0.1, BETA=0.05, ETA=(+1,-1,-1,-1)
// f64 replica of the JAX reference. jnp.linalg.pinv default rcond
//   = 10*max(M,N)*eps_f32 = 4.76837158203125e-6 (verified round 4).
// Round 6: two-phase compaction. Kernel 1 = fast Sherman-Morrison path for
// provably-safe lanes (min|lambda| > 6*cutoff via det/sigma bounds); unsafe
// lanes (~2e-3 of particles) are appended to a list in d_ws. Kernel 2 runs
// the Jacobi+truncated-pinv on the compacted list only (dense waves, no
// divergence tail).

#define SIX_RCOND 2.86102294921875e-5   // 6 * 4.76837158203125e-6
#define RCOND     4.76837158203125e-6

__device__ __forceinline__ void model_terms(
    const double* sW, const double* sV,
    const double x[4], const double u[4],
    double A[4], double f[4], double d[4])
{
    const double eta[4] = {1.0, -1.0, -1.0, -1.0};
    const double CHG = 0.5, ALPHA = 0.1, BETA = 0.05;
    double G[4][4];
    #pragma unroll
    for (int j = 0; j < 4; ++j) {
        double t = 0.0, s = 0.0;
        #pragma unroll
        for (int k = 0; k < 4; ++k) { t += sW[j*4+k]*x[k]; s += sV[j*4+k]*x[k]; }
        double th = tanh(t);
        A[j] = th + s;
        double dth = 1.0 - th * th;
        #pragma unroll
        for (int k = 0; k < 4; ++k) G[j][k] = dth * sW[j*4+k] + sV[j*4+k];
    }
    double S = 0.0;
    #pragma unroll
    for (int k = 0; k < 4; ++k) S += u[k] * A[k];
    double P[4], R[4], Q[4];
    #pragma unroll
    for (int j = 0; j < 4; ++j) {
        double p = 0.0, r = 0.0, q = 0.0;
        #pragma unroll
        for (int k = 0; k < 4; ++k) {
            p += G[k][j] * u[k];
            r += G[j][k] * u[k];
            q += G[k][j] * (CHG * eta[k]) * u[k];
        }
        P[j] = p; R[j] = r; Q[j] = q;
    }
    double T = 0.0;
    #pragma unroll
    for (int j = 0; j < 4; ++j) T += u[j] * R[j];
    #pragma unroll
    for (int j = 0; j < 4; ++j) {
        f[j] = -2.0 * ALPHA * x[j] * u[j] * u[j]
             + Q[j]
             + 2.0 * BETA * S * P[j]
             - (CHG * eta[j] + 2.0 * BETA * S) * R[j]
             - 2.0 * BETA * A[j] * T;
        d[j] = eta[j] + 2.0 * ALPHA * x[j] * x[j];
    }
}

__device__ __forceinline__ void sm_solve(
    const double d[4], const double A[4], const double f[4], double acc[4])
{
    const double C2 = 0.1;
    double b[4], fd[4], den = 1.0, w = 0.0;
    #pragma unroll
    for (int j = 0; j < 4; ++j) {
        double inv = 1.0 / d[j];
        b[j]  = A[j] * inv;
        fd[j] = f[j] * inv;
        den  += C2 * A[j] * b[j];
        w    += b[j] * f[j];
    }
    double scale = C2 * w / den;
    #pragma unroll
    for (int j = 0; j < 4; ++j) acc[j] = fd[j] - b[j] * scale;
}

__device__ void jacobi_pinv_solve(
    const double d[4], const double A[4], const double f[4], double acc[4])
{
    const double C2 = 0.1;
    double M[4][4], Vm[4][4];
    #pragma unroll
    for (int r = 0; r < 4; ++r) {
        #pragma unroll
        for (int c = 0; c < 4; ++c) {
            M[r][c] = C2 * A[r] * A[c];
            Vm[r][c] = (r == c) ? 1.0 : 0.0;
        }
        M[r][r] += d[r];
    }
    for (int sweep = 0; sweep < 8; ++sweep) {
        #pragma unroll
        for (int p = 0; p < 3; ++p) {
            #pragma unroll
            for (int q2 = p + 1; q2 < 4; ++q2) {
                double apq = M[p][q2];
                if (fabs(apq) < 1e-280) continue;
                double app = M[p][p], aqq = M[q2][q2];
                double tau = (aqq - app) / (2.0 * apq);
                double tt = ((tau >= 0.0) ? 1.0 : -1.0) /
                            (fabs(tau) + sqrt(1.0 + tau * tau));
                double c = 1.0 / sqrt(1.0 + tt * tt);
                double s = tt * c;
                #pragma unroll
                for (int k = 0; k < 4; ++k) {
                    double mkp = M[k][p], mkq = M[k][q2];
                    M[k][p]  = c * mkp - s * mkq;
                    M[k][q2] = s * mkp + c * mkq;
                }
                #pragma unroll
                for (int k = 0; k < 4; ++k) {
                    double mpk = M[p][k], mqk = M[q2][k];
                    M[p][k]  = c * mpk - s * mqk;
                    M[q2][k] = s * mpk + c * mqk;
                }
                #pragma unroll
                for (int k = 0; k < 4; ++k) {
                    double vkp = Vm[k][p], vkq = Vm[k][q2];
                    Vm[k][p]  = c * vkp - s * vkq;
                    Vm[k][q2] = s * vkp + c * vkq;
                }
            }
        }
    }
    double lam[4], sigmax = 0.0;
    #pragma unroll
    for (int k = 0; k < 4; ++k) {
        lam[k] = M[k][k];
        double a = fabs(lam[k]);
        sigmax = (a > sigmax) ? a : sigmax;
    }
    double cutoff = RCOND * sigmax;
    #pragma unroll
    for (int j = 0; j < 4; ++j) acc[j] = 0.0;
    #pragma unroll
    for (int e = 0; e < 4; ++e) {
        if (fabs(lam[e]) > cutoff) {
            double coef = 0.0;
            #pragma unroll
            for (int k = 0; k < 4; ++k) coef += Vm[k][e] * f[k];
            coef /= lam[e];
            #pragma unroll
            for (int j = 0; j < 4; ++j) acc[j] += coef * Vm[j][e];
        }
    }
}

// ---------------- Phase 1: fast path + compaction of unsafe lanes ----------
__global__ __launch_bounds__(256) void fast_kernel(
    const float* __restrict__ y, const float* __restrict__ W,
    const float* __restrict__ V, float* __restrict__ out,
    unsigned int* __restrict__ cnt, int* __restrict__ list,
    unsigned int cap, int B)
{
    __shared__ double sW[16], sV[16];
    if (threadIdx.x < 16)      sW[threadIdx.x]      = (double)W[threadIdx.x];
    else if (threadIdx.x < 32) sV[threadIdx.x - 16] = (double)V[threadIdx.x - 16];
    __syncthreads();

    int i = blockIdx.x * blockDim.x + threadIdx.x;
    if (i >= B) return;

    const float4* y4 = (const float4*)y;
    float4 xv = y4[2 * i];
    float4 uv = y4[2 * i + 1];
    double x[4] = {xv.x, xv.y, xv.z, xv.w};
    double u[4] = {uv.x, uv.y, uv.z, uv.w};

    double A[4], f[4], d[4];
    model_terms(sW, sV, x, u, A, f, d);

    const double C2 = 0.1;
    double mind = 1e300;
    #pragma unroll
    for (int j = 0; j < 4; ++j) {
        double a = fabs(d[j]);
        mind = (a < mind) ? a : mind;
    }
    // det(J) = prod(d) + C2 * sum_i A_i^2 * prod_{j!=i} d_j
    double p01 = d[0] * d[1], p23 = d[2] * d[3];
    double det = p01 * p23
        + C2 * (A[0]*A[0]*(d[1]*p23) + A[1]*A[1]*(d[0]*p23) +
                A[2]*A[2]*(p01*d[3]) + A[3]*A[3]*(p01*d[2]));
    // sigma_max^2 upper bound: min(Frobenius^2, (max row sum)^2)
    double sumA2 = 0.0, sumA4 = 0.0, F2 = 0.0;
    #pragma unroll
    for (int j = 0; j < 4; ++j) {
        double Aj2 = A[j] * A[j];
        sumA2 += Aj2; sumA4 += Aj2 * Aj2;
        double Jjj = d[j] + C2 * Aj2;
        F2 += Jjj * Jjj;
    }
    F2 += C2 * C2 * (sumA2 * sumA2 - sumA4);
    double rowmax = 0.0;
    #pragma unroll
    for (int r = 0; r < 4; ++r) {
        double rs = 0.0;
        #pragma unroll
        for (int c = 0; c < 4; ++c) {
            double Jrc = C2 * A[r] * A[c] + ((r == c) ? d[r] : 0.0);
            rs += fabs(Jrc);
        }
        rowmax = (rs > rowmax) ? rs : rowmax;
    }
    double sig_hi2 = rowmax * rowmax;
    sig_hi2 = (F2 < sig_hi2) ? F2 : sig_hi2;
    // |det| > 6*rcond*sig_hi^4  =>  min|lambda| > 6*cutoff => pinv == inv
    bool safe = (fabs(det) > SIX_RCOND * sig_hi2 * sig_hi2) && (mind > 1e-3);

    if (safe) {
        double acc[4];
        sm_solve(d, A, f, acc);
        float4 res;
        res.x = (float)acc[0]; res.y = (float)acc[1];
        res.z = (float)acc[2]; res.w = (float)acc[3];
        ((float4*)out)[i] = res;
    } else {
        unsigned int idx = atomicAdd(cnt, 1u);
        if (idx < cap) {
            list[idx] = i;           // deferred to phase 2
        } else {
            // ws overflow (can't happen at expected rates): best-effort SM
            double acc[4];
            sm_solve(d, A, f, acc);
            float4 res;
            res.x = (float)acc[0]; res.y = (float)acc[1];
            res.z = (float)acc[2]; res.w = (float)acc[3];
            ((float4*)out)[i] = res;
        }
    }
}

// ---------------- Phase 2: dense Jacobi over the compacted list -----------
__global__ __launch_bounds__(256) void slow_kernel(
    const float* __restrict__ y, const float* __restrict__ W,
    const float* __restrict__ V, float* __restrict__ out,
    const unsigned int* __restrict__ cnt, const int* __restrict__ list,
    unsigned int cap)
{
    __shared__ double sW[16], sV[16];
    if (threadIdx.x < 16)      sW[threadIdx.x]      = (double)W[threadIdx.x];
    else if (threadIdx.x < 32) sV[threadIdx.x - 16] = (double)V[threadIdx.x - 16];
    __syncthreads();

    unsigned int n = *cnt;
    if (n > cap) n = cap;
    int stride = gridDim.x * blockDim.x;
    for (unsigned int j = blockIdx.x * blockDim.x + threadIdx.x; j < n; j += stride) {
        int i = list[j];
        const float4* y4 = (const float4*)y;
        float4 xv = y4[2 * i];
        float4 uv = y4[2 * i + 1];
        double x[4] = {xv.x, xv.y, xv.z, xv.w};
        double u[4] = {uv.x, uv.y, uv.z, uv.w};
        double A[4], f[4], d[4];
        model_terms(sW, sV, x, u, A, f, d);
        double acc[4];
        jacobi_pinv_solve(d, A, f, acc);
        float4 res;
        res.x = (float)acc[0]; res.y = (float)acc[1];
        res.z = (float)acc[2]; res.w = (float)acc[3];
        ((float4*)out)[i] = res;
    }
}

extern "C" void kernel_launch(void* const* d_in, const int* in_sizes, int n_in,
                              void* d_out, int out_size, void* d_ws, size_t ws_size,
                              hipStream_t stream) {
    const float* y = (const float*)d_in[0];
    const float* W = (const float*)d_in[1];
    const float* V = (const float*)d_in[2];
    float* out = (float*)d_out;
    int B = in_sizes[0] / 8;

    unsigned int* cnt = (unsigned int*)d_ws;
    int* list = (int*)((char*)d_ws + 16);
    unsigned int cap = (ws_size > 16) ? (unsigned int)((ws_size - 16) / sizeof(int)) : 0u;
    if (cap > (unsigned int)B) cap = (unsigned int)B;

    hipMemsetAsync(d_ws, 0, 16, stream);   // zero the counter (capture-legal)

    int block = 256;
    int grid = (B + block - 1) / block;
    fast_kernel<<<grid, block, 0, stream>>>(y, W, V, out, cnt, list, cap, B);
    slow_kernel<<<64, block, 0, stream>>>(y, W, V, out, cnt, list, cap);
}